// Round 5
// baseline (229.943 us; speedup 1.0000x reference)
//
#include <hip/hip_runtime.h>

#define HID 2048
#define NEXP 64
#define NTOK 16384
#define TM 32            // tokens per block (one 32-row MFMA tile)
#define NTHREADS 256
#define NBLK (NTOK / TM)     // 512
#define NCHUNK 32            // HID / 64
#define KPH 4                // K-phases = waves per block
#define CPW 8                // chunks per wave
#define CHUNK_B 24576        // 4 ksteps * 3 planes * 2 groups * 1024 B
#define WS_W_OFF 262144      // W planes start here; partials in [0, 512*128 floats)

// out layout (f32): weights [0,32768) | indices [32768,65536) | aux 65536 | counts [65537,65601)
#define OUT_IDX_OFF (2 * NTOK)
#define OUT_AUX_OFF (4 * NTOK)
#define OUT_CNT_OFF (4 * NTOK + 1)

typedef __attribute__((ext_vector_type(8))) short bhalf8;    // 8 bf16 = 4 VGPRs (A/B frag)
typedef __attribute__((ext_vector_type(16))) float f32x16;   // 32x32 C/D frag

// Exact 3-way RNE bf16 split (for W, precomputed): v == h1+h2+h3 exactly.
__device__ __forceinline__ void split3(float v, unsigned short& h1, unsigned short& h2, unsigned short& h3) {
    unsigned int u = __float_as_uint(v);
    unsigned int r1 = (u + 0x7FFFu + ((u >> 16) & 1u)) & 0xFFFF0000u;
    float f1 = __uint_as_float(r1);
    float d1 = v - f1;
    unsigned int u2 = __float_as_uint(d1);
    unsigned int r2 = (u2 + 0x7FFFu + ((u2 >> 16) & 1u)) & 0xFFFF0000u;
    float f2 = __uint_as_float(r2);
    float d2 = d1 - f2;
    h1 = (unsigned short)(r1 >> 16);
    h2 = (unsigned short)(r2 >> 16);
    h3 = (unsigned short)(__float_as_uint(d2) >> 16);
}

// Truncating 3-plane split of 8 fp32 -> three bf16x8 A-frags, in registers.
__device__ __forceinline__ void xsplit(float4 va, float4 vb, bhalf8& o1, bhalf8& o2, bhalf8& o3) {
    float f[8] = {va.x, va.y, va.z, va.w, vb.x, vb.y, vb.z, vb.w};
    union U { bhalf8 v; unsigned int u[4]; } u1, u2, u3;
#pragma unroll
    for (int t = 0; t < 4; t++) {
        float a = f[2 * t], b = f[2 * t + 1];
        unsigned int ua = __float_as_uint(a), ub = __float_as_uint(b);
        float da = a - __uint_as_float(ua & 0xFFFF0000u);
        float db = b - __uint_as_float(ub & 0xFFFF0000u);
        unsigned int uda = __float_as_uint(da), udb = __float_as_uint(db);
        float da2 = da - __uint_as_float(uda & 0xFFFF0000u);
        float db2 = db - __uint_as_float(udb & 0xFFFF0000u);
        u1.u[t] = (ua >> 16) | (ub & 0xFFFF0000u);
        u2.u[t] = (uda >> 16) | (udb & 0xFFFF0000u);
        u3.u[t] = (__float_as_uint(da2) >> 16) | (__float_as_uint(db2) & 0xFFFF0000u);
    }
    o1 = u1.v; o2 = u2.v; o3 = u3.v;
}

// ---- pre-kernel: split W into 3 bf16 planes in coalesced B-fragment layout ----
// byte offset = (((c*4+ks)*3 + plane)*2 + group)*1024 + l*16, l = (e&31) + 32*((k>>3)&1)
__global__ __launch_bounds__(256) void wsplit_kernel(const float* __restrict__ W,
                                                     char* __restrict__ wq) {
    int idx8 = (blockIdx.x * 256 + threadIdx.x) * 8;
    int e = idx8 >> 11;
    int k0 = idx8 & 2047;
    int c = k0 >> 6, ks = (k0 >> 4) & 3, half = (k0 >> 3) & 1;
    int g = e >> 5, l = (e & 31) + 32 * half;
    const float4* wp = (const float4*)(W + (size_t)e * HID + k0);
    float4 v0 = wp[0], v1 = wp[1];
    float f[8] = {v0.x, v0.y, v0.z, v0.w, v1.x, v1.y, v1.z, v1.w};
    unsigned int p1[4], p2[4], p3[4];
#pragma unroll
    for (int t = 0; t < 4; t++) {
        unsigned short a1, a2, a3, b1, b2, b3;
        split3(f[2 * t], a1, a2, a3);
        split3(f[2 * t + 1], b1, b2, b3);
        p1[t] = (unsigned int)a1 | ((unsigned int)b1 << 16);
        p2[t] = (unsigned int)a2 | ((unsigned int)b2 << 16);
        p3[t] = (unsigned int)a3 | ((unsigned int)b3 << 16);
    }
    char* base = wq + (size_t)(((c * 4 + ks) * 3 + 0) * 2 + g) * 1024 + l * 16;
    *(uint4*)(base)        = make_uint4(p1[0], p1[1], p1[2], p1[3]);
    *(uint4*)(base + 2048) = make_uint4(p2[0], p2[1], p2[2], p2[3]);
    *(uint4*)(base + 4096) = make_uint4(p3[0], p3[1], p3[2], p3[3]);
}

__device__ __forceinline__ void load_chunk(const float* xc, float4 (&pa)[4], float4 (&pb)[4]) {
#pragma unroll
    for (int ks = 0; ks < 4; ks++) {
        pa[ks] = *(const float4*)(xc + ks * 16);
        pb[ks] = *(const float4*)(xc + ks * 16 + 4);
    }
}

__device__ __forceinline__ void compute_chunk(const float4 (&pa)[4], const float4 (&pb)[4],
                                              const char* wc, f32x16& acc0, f32x16& acc1) {
#pragma unroll
    for (int ks = 0; ks < 4; ks++) {
        bhalf8 A1, A2, A3;
        xsplit(pa[ks], pb[ks], A1, A2, A3);
        const char* wk = wc + ks * 6144;
        bhalf8 B1 = *(const bhalf8*)(wk);
        bhalf8 B2 = *(const bhalf8*)(wk + 2048);
        bhalf8 B3 = *(const bhalf8*)(wk + 4096);
        acc0 = __builtin_amdgcn_mfma_f32_32x32x16_bf16(A1, B1, acc0, 0, 0, 0);
        acc0 = __builtin_amdgcn_mfma_f32_32x32x16_bf16(A1, B2, acc0, 0, 0, 0);
        acc0 = __builtin_amdgcn_mfma_f32_32x32x16_bf16(A2, B1, acc0, 0, 0, 0);
        acc0 = __builtin_amdgcn_mfma_f32_32x32x16_bf16(A1, B3, acc0, 0, 0, 0);
        acc0 = __builtin_amdgcn_mfma_f32_32x32x16_bf16(A2, B2, acc0, 0, 0, 0);
        acc0 = __builtin_amdgcn_mfma_f32_32x32x16_bf16(A3, B1, acc0, 0, 0, 0);
        bhalf8 C1 = *(const bhalf8*)(wk + 1024);
        bhalf8 C2 = *(const bhalf8*)(wk + 2048 + 1024);
        bhalf8 C3 = *(const bhalf8*)(wk + 4096 + 1024);
        acc1 = __builtin_amdgcn_mfma_f32_32x32x16_bf16(A1, C1, acc1, 0, 0, 0);
        acc1 = __builtin_amdgcn_mfma_f32_32x32x16_bf16(A1, C2, acc1, 0, 0, 0);
        acc1 = __builtin_amdgcn_mfma_f32_32x32x16_bf16(A2, C1, acc1, 0, 0, 0);
        acc1 = __builtin_amdgcn_mfma_f32_32x32x16_bf16(A1, C3, acc1, 0, 0, 0);
        acc1 = __builtin_amdgcn_mfma_f32_32x32x16_bf16(A2, C2, acc1, 0, 0, 0);
        acc1 = __builtin_amdgcn_mfma_f32_32x32x16_bf16(A3, C1, acc1, 0, 0, 0);
    }
}

__global__ __launch_bounds__(NTHREADS, 2) void router_main(
    const float* __restrict__ x, const char* __restrict__ wq,
    float* __restrict__ out, float* __restrict__ partials)
{
    __shared__ float slab[KPH * TM * 68];   // 34816 B: per-kphase partial logits
    __shared__ float smax[TM];
    __shared__ float sinvZ[TM];
    __shared__ float scount[NEXP];
    __shared__ float sprob[NEXP];

    const int tid = threadIdx.x;
    const int w = tid >> 6;        // kphase
    const int lane = tid & 63;
    const int r = lane & 31;       // A row (token); B expert within group
    const int h = lane >> 5;       // k-octet half
    const int n0 = blockIdx.x * TM;

    const float* xrow = x + (size_t)(n0 + r) * HID + h * 8;

    f32x16 acc0, acc1;
#pragma unroll
    for (int i = 0; i < 16; i++) { acc0[i] = 0.f; acc1[i] = 0.f; }

    // ---- free-running K-loop, 2-deep x register double-buffer, no barriers ----
    float4 pa0[4], pb0[4], pa1[4], pb1[4];
    const float* xbase = xrow + (w * CPW) * 64;
    load_chunk(xbase, pa0, pb0);
    const char* wcbase = wq + (size_t)(w * CPW) * CHUNK_B + lane * 16;

#pragma unroll 1
    for (int i = 0; i < CPW; i += 2) {
        if (i + 1 < CPW) load_chunk(xbase + (i + 1) * 64, pa1, pb1);
        compute_chunk(pa0, pb0, wcbase + (size_t)i * CHUNK_B, acc0, acc1);
        if (i + 2 < CPW) load_chunk(xbase + (i + 2) * 64, pa0, pb0);
        if (i + 1 < CPW) compute_chunk(pa1, pb1, wcbase + (size_t)(i + 1) * CHUNK_B, acc0, acc1);
    }

    // ---- combine: each wave stores its partial tile to its slab ----
    // C/D 32x32 layout: col = lane&31, row = (reg&3) + 8*(reg>>2) + 4*(lane>>5)  [m74/m101]
#pragma unroll
    for (int reg = 0; reg < 16; reg++) {
        int row = (reg & 3) + 8 * (reg >> 2) + 4 * h;
        slab[(w * TM + row) * 68 + r]      = acc0[reg];
        slab[(w * TM + row) * 68 + 32 + r] = acc1[reg];
    }
    if (tid < NEXP) { scount[tid] = 0.f; sprob[tid] = 0.f; }
    __syncthreads();

    // reduce 4 kphase slabs into slab[0]
    float* logits = slab;
#pragma unroll
    for (int idx = tid; idx < TM * NEXP; idx += NTHREADS) {
        int t = idx >> 6, e = idx & 63;
        logits[t * 68 + e] = slab[(0 * TM + t) * 68 + e] + slab[(1 * TM + t) * 68 + e]
                           + slab[(2 * TM + t) * 68 + e] + slab[(3 * TM + t) * 68 + e];
    }
    __syncthreads();

    // phase A: per-token top-2 + softmax stats + weight/index writes (LDS atomics only)
    if (tid < TM) {
        const int t = tid;
        float m1 = -3.4e38f, m2 = -3.4e38f;
        int i1 = 0, i2 = 0;
        for (int e = 0; e < NEXP; e++) {
            float v = logits[t * 68 + e];
            if (v > m1) { m2 = m1; i2 = i1; m1 = v; i1 = e; }
            else if (v > m2) { m2 = v; i2 = e; }
        }
        float Z = 0.f;
        for (int e = 0; e < NEXP; e++)
            Z += __expf(logits[t * 68 + e] - m1);
        float invZ = 1.f / Z;
        float p1 = invZ;
        float p2 = __expf(m2 - m1) * invZ;
        float denom = p1 + p2 + 1e-6f;
        int n = n0 + t;
        out[2 * n + 0] = p1 / denom;
        out[2 * n + 1] = p2 / denom;
        out[OUT_IDX_OFF + 2 * n + 0] = (float)i1;
        out[OUT_IDX_OFF + 2 * n + 1] = (float)i2;
        smax[t] = m1;
        sinvZ[t] = invZ;
        atomicAdd(&scount[i1], 1.f);
        atomicAdd(&scount[i2], 1.f);
    }
    __syncthreads();

    // phase B: per-expert prob partial over this block's 32 tokens (parallel, LDS atomics)
    {
        const int e = tid & 63, tq = tid >> 6;
        float s = 0.f;
#pragma unroll
        for (int j = 0; j < 8; j++) {
            int t = tq * 8 + j;
            s += __expf(logits[t * 68 + e] - smax[t]) * sinvZ[t];
        }
        atomicAdd(&sprob[e], s);
    }
    __syncthreads();

    // non-atomic per-block partial store (no global atomics anywhere)
    if (tid < NEXP) {
        partials[blockIdx.x * 128 + tid]      = sprob[tid];
        partials[blockIdx.x * 128 + 64 + tid] = scount[tid];
    }
}

__global__ __launch_bounds__(128) void router_finish(const float* __restrict__ partials,
                                                     float* __restrict__ out)
{
    __shared__ float red[2];
    const int t = threadIdx.x;   // 0..127; col t: [0,64)=prob sums, [64,128)=counts
    float s = 0.f;
#pragma unroll 8
    for (int b = 0; b < NBLK; b++)
        s += partials[b * 128 + t];
    const float invN = 1.f / (float)NTOK;
    if (t >= 64) out[OUT_CNT_OFF + (t - 64)] = s;
    float sc = s * invN;
    float v = sc * sc;
#pragma unroll
    for (int off = 32; off > 0; off >>= 1)
        v += __shfl_down(v, off);
    if ((t & 63) == 0) red[t >> 6] = v;
    __syncthreads();
    if (t == 0) out[OUT_AUX_OFF] = (red[0] + red[1]) * (float)NEXP;
}

extern "C" void kernel_launch(void* const* d_in, const int* in_sizes, int n_in,
                              void* d_out, int out_size, void* d_ws, size_t ws_size,
                              hipStream_t stream)
{
    const float* x = (const float*)d_in[0];   // [4,4096,2048] f32
    const float* W = (const float*)d_in[1];   // [64,2048] f32
    float* out = (float*)d_out;
    float* partials = (float*)d_ws;           // 512 blocks x 128 floats = 256 KB
    char* wq = (char*)d_ws + WS_W_OFF;        // W planes: 768 KB

    wsplit_kernel<<<64, 256, 0, stream>>>(W, wq);
    router_main<<<NBLK, NTHREADS, 0, stream>>>(x, wq, out, partials);
    router_finish<<<1, 128, 0, stream>>>(partials, out);
}